// Round 8
// baseline (62.112 us; speedup 1.0000x reference)
//
#include <hip/hip_runtime.h>

// LinearImputer: linear interp over zero runs along time axis (B=32,T=4096,D=256 f32).
// Semantics (match JAX ref):
//   prev = last valid <= t (-1 if none); nxt = first valid >= t (T if none)
//   interior = !valid && prev>=0 && nxt<T
//   denom = max(nxt-prev-2, 1); pos = t-prev-1; out = x[prev] + (x[nxt]-x[prev])*pos/denom
// Boundary-touching runs stay zero.
//
// R8: convoy-breaking. Each thread owns rows [t0, t0+16) as halves A,B of 8 rows.
//  - ONE 24-load burst (4 back-halo + 8 A + 8 B + 4 fwd-halo) per 64 elements
//    (was 18 per 32): stall-per-compute halves, issued B/elem 9 -> 6.
//  - B's prev-carry = A's forward carry (free, exact). A's next-seed = scan of B's
//    registers, falling back to B's next-seed. Only 2 rare global-walk sites/thread.
//  - Emit keeps the R3 quadratic per-half scan (R4/R5 lesson: op-count conserved
//    restructurings lose; R6 lesson: never cap VGPR via launch_bounds min-waves).

typedef float f32x4 __attribute__((ext_vector_type(4)));

constexpr int B = 32, T = 4096, D = 256;
constexpr int L  = 8;         // rows per half
constexpr int W  = 4;         // halo rows prefetched per side
constexpr int NC2 = T / (2 * L);   // 256 double-chunks per column
constexpr int C4 = D / 4;     // 64

__global__ __launch_bounds__(256)
void LinearImputer_kernel(const float* __restrict__ x, float* __restrict__ out) {
    const int g  = blockIdx.x * 256 + threadIdx.x;
    const int l  = g & (C4 - 1);         // float4 column group (== lane)
    const int bc = g >> 6;
    const int c  = bc & (NC2 - 1);       // double-chunk index (wave-uniform)
    const int b  = bc >> 8;              // NC2 = 256
    const int tA0 = c * (2 * L);
    const int tB0 = tA0 + L;
    const int tEnd = tA0 + 2 * L;

    const f32x4* __restrict__ x4 = (const f32x4*)x;
    f32x4* __restrict__       o4 = (f32x4*)out;
    const size_t base = ((size_t)b * T) * C4 + l;

    const bool hasB = (c > 0);           // wave-uniform
    const bool hasF = (c < NC2 - 1);

    // ---- ONE load burst: 4 back-halo + 8 A + 8 B + 4 fwd-halo ----
    f32x4 hb4[W], hf4[W];
    if (hasB) {
        #pragma unroll
        for (int w = 0; w < W; ++w) hb4[w] = x4[base + (size_t)(tA0 - 1 - w) * C4];
    }
    if (hasF) {
        #pragma unroll
        for (int w = 0; w < W; ++w) hf4[w] = x4[base + (size_t)(tEnd + w) * C4];
    }
    float vA[L][4], vB[L][4];
    #pragma unroll
    for (int j = 0; j < L; ++j) {
        f32x4 tv = x4[base + (size_t)(tA0 + j) * C4];
        vA[j][0] = tv.x; vA[j][1] = tv.y; vA[j][2] = tv.z; vA[j][3] = tv.w;
    }
    #pragma unroll
    for (int j = 0; j < L; ++j) {
        f32x4 tv = x4[base + (size_t)(tB0 + j) * C4];
        vB[j][0] = tv.x; vB[j][1] = tv.y; vB[j][2] = tv.z; vB[j][3] = tv.w;
    }

    // ---- backward halo -> prev carry (pi,pv) for half A ----
    int pi[4]; float pv[4];
    #pragma unroll
    for (int cc = 0; cc < 4; ++cc) { pi[cc] = -1; pv[cc] = 0.0f; }
    if (hasB) {
        #pragma unroll
        for (int w = 0; w < W; ++w) {
            float h[4] = {hb4[w].x, hb4[w].y, hb4[w].z, hb4[w].w};
            #pragma unroll
            for (int cc = 0; cc < 4; ++cc)
                if (pi[cc] < 0 && h[cc] != 0.0f) { pi[cc] = tA0 - 1 - w; pv[cc] = h[cc]; }
        }
        // rare deep-run fallback, 2 rows/iter
        int pending = 0;
        #pragma unroll
        for (int cc = 0; cc < 4; ++cc)
            if (vA[0][cc] == 0.0f && pi[cc] < 0) pending |= (1 << cc);
        if (pending) {
            int tt = tA0 - 1 - W;
            while (pending && tt >= 0) {
                f32x4 a0 = x4[base + (size_t)tt * C4];
                const bool has2 = (tt - 1) >= 0;
                f32x4 a1;
                if (has2) a1 = x4[base + (size_t)(tt - 1) * C4];
                float h0[4] = {a0.x, a0.y, a0.z, a0.w};
                #pragma unroll
                for (int cc = 0; cc < 4; ++cc)
                    if (((pending >> cc) & 1) && h0[cc] != 0.0f) {
                        pi[cc] = tt; pv[cc] = h0[cc]; pending &= ~(1 << cc);
                    }
                if (has2 && pending) {
                    float h1[4] = {a1.x, a1.y, a1.z, a1.w};
                    #pragma unroll
                    for (int cc = 0; cc < 4; ++cc)
                        if (((pending >> cc) & 1) && h1[cc] != 0.0f) {
                            pi[cc] = tt - 1; pv[cc] = h1[cc]; pending &= ~(1 << cc);
                        }
                }
                tt -= 2;
            }
        }
    }

    // ---- forward halo -> next seed for half B (niB,nvB) ----
    int niB[4]; float nvB[4];
    #pragma unroll
    for (int cc = 0; cc < 4; ++cc) { niB[cc] = T; nvB[cc] = 0.0f; }
    if (hasF) {
        #pragma unroll
        for (int w = 0; w < W; ++w) {
            float h[4] = {hf4[w].x, hf4[w].y, hf4[w].z, hf4[w].w};
            #pragma unroll
            for (int cc = 0; cc < 4; ++cc)
                if (niB[cc] == T && h[cc] != 0.0f) { niB[cc] = tEnd + w; nvB[cc] = h[cc]; }
        }
        int pending = 0;
        #pragma unroll
        for (int cc = 0; cc < 4; ++cc)
            if (vB[L - 1][cc] == 0.0f && niB[cc] == T) pending |= (1 << cc);
        if (pending) {
            int tt = tEnd + W;
            while (pending && tt < T) {
                f32x4 a0 = x4[base + (size_t)tt * C4];
                const bool has2 = (tt + 1) < T;
                f32x4 a1;
                if (has2) a1 = x4[base + (size_t)(tt + 1) * C4];
                float h0[4] = {a0.x, a0.y, a0.z, a0.w};
                #pragma unroll
                for (int cc = 0; cc < 4; ++cc)
                    if (((pending >> cc) & 1) && h0[cc] != 0.0f) {
                        niB[cc] = tt; nvB[cc] = h0[cc]; pending &= ~(1 << cc);
                    }
                if (has2 && pending) {
                    float h1[4] = {a1.x, a1.y, a1.z, a1.w};
                    #pragma unroll
                    for (int cc = 0; cc < 4; ++cc)
                        if (((pending >> cc) & 1) && h1[cc] != 0.0f) {
                            niB[cc] = tt + 1; nvB[cc] = h1[cc]; pending &= ~(1 << cc);
                        }
                }
                tt += 2;
            }
        }
    }

    // ---- next seed for half A: first valid in B's registers, else B's seed ----
    int niA[4]; float nvA[4];
    #pragma unroll
    for (int cc = 0; cc < 4; ++cc) { niA[cc] = niB[cc]; nvA[cc] = nvB[cc]; }
    #pragma unroll
    for (int k = L - 1; k >= 0; --k) {
        #pragma unroll
        for (int cc = 0; cc < 4; ++cc)
            if (vB[k][cc] != 0.0f) { niA[cc] = tB0 + k; nvA[cc] = vB[k][cc]; }
    }

    // ---- emit half A: prev-carry + quadratic in-half next-scan ----
    #pragma unroll
    for (int j = 0; j < L; ++j) {
        float o[4];
        #pragma unroll
        for (int cc = 0; cc < 4; ++cc) {
            float val = vA[j][cc];
            if (val != 0.0f) {
                o[cc] = val; pi[cc] = tA0 + j; pv[cc] = val;
            } else {
                int nxi = niA[cc]; float nxv = nvA[cc];
                #pragma unroll
                for (int k = L - 1; k > j; --k)
                    if (vA[k][cc] != 0.0f) { nxi = tA0 + k; nxv = vA[k][cc]; }
                if (pi[cc] >= 0 && nxi < T) {
                    int denom = nxi - pi[cc] - 2;
                    if (denom < 1) denom = 1;
                    float frac = __fdividef((float)(tA0 + j - pi[cc] - 1), (float)denom);
                    o[cc] = pv[cc] + (nxv - pv[cc]) * frac;
                } else {
                    o[cc] = 0.0f;
                }
            }
        }
        f32x4 ov; ov.x = o[0]; ov.y = o[1]; ov.z = o[2]; ov.w = o[3];
        __builtin_nontemporal_store(ov, &o4[base + (size_t)(tA0 + j) * C4]);
    }

    // ---- emit half B: carry (pi,pv) continues from A — exact and free ----
    #pragma unroll
    for (int j = 0; j < L; ++j) {
        float o[4];
        #pragma unroll
        for (int cc = 0; cc < 4; ++cc) {
            float val = vB[j][cc];
            if (val != 0.0f) {
                o[cc] = val; pi[cc] = tB0 + j; pv[cc] = val;
            } else {
                int nxi = niB[cc]; float nxv = nvB[cc];
                #pragma unroll
                for (int k = L - 1; k > j; --k)
                    if (vB[k][cc] != 0.0f) { nxi = tB0 + k; nxv = vB[k][cc]; }
                if (pi[cc] >= 0 && nxi < T) {
                    int denom = nxi - pi[cc] - 2;
                    if (denom < 1) denom = 1;
                    float frac = __fdividef((float)(tB0 + j - pi[cc] - 1), (float)denom);
                    o[cc] = pv[cc] + (nxv - pv[cc]) * frac;
                } else {
                    o[cc] = 0.0f;
                }
            }
        }
        f32x4 ov; ov.x = o[0]; ov.y = o[1]; ov.z = o[2]; ov.w = o[3];
        __builtin_nontemporal_store(ov, &o4[base + (size_t)(tB0 + j) * C4]);
    }
}

extern "C" void kernel_launch(void* const* d_in, const int* in_sizes, int n_in,
                              void* d_out, int out_size, void* d_ws, size_t ws_size,
                              hipStream_t stream) {
    const float* x = (const float*)d_in[0];
    float* out = (float*)d_out;
    const int total_threads = B * NC2 * C4;   // 524,288
    dim3 grid(total_threads / 256), block(256);
    LinearImputer_kernel<<<grid, block, 0, stream>>>(x, out);
}

// Round 9
// 61.019 us; speedup vs baseline: 1.0179x; 1.0179x over previous
//
#include <hip/hip_runtime.h>

// LinearImputer: linear interp over zero runs along time axis (B=32,T=4096,D=256 f32).
// Semantics (match JAX ref):
//   prev = last valid <= t (-1 if none); nxt = first valid >= t (T if none)
//   interior = !valid && prev>=0 && nxt<T
//   denom = max(nxt-prev-2, 1); pos = t-prev-1; out = x[prev] + (x[nxt]-x[prev])*pos/denom
// Boundary-touching runs stay zero.
//
// R9 = R7 body EXACTLY (best 54.1us, VGPR 52), single delta: block 256 -> 1024
// (grid 4096 -> 1024 WGs). Tests the dispatch/residency hypothesis: measured
// occupancy was 33-40% despite VGPR allowing 8 waves/SIMD; 16-wave WGs fill a CU
// with 2 blocks. R4/R8 lesson: keep VGPR ~50 (both 90+ variants lost 8us).
// R6 lesson: no launch_bounds min-waves pin (VGPR cap serializes the load burst).

typedef float f32x4 __attribute__((ext_vector_type(4)));

constexpr int B = 32, T = 4096, D = 256;
constexpr int L = 8;        // rows per thread
constexpr int W = 5;        // halo rows prefetched per side
constexpr int NC = T / L;   // 512
constexpr int C4 = D / 4;   // 64
constexpr int BLK = 1024;   // threads per block

__global__ __launch_bounds__(BLK)
void LinearImputer_kernel(const float* __restrict__ x, float* __restrict__ out) {
    const int g  = blockIdx.x * BLK + threadIdx.x;
    const int l  = g & (C4 - 1);        // float4 column group
    const int bc = g >> 6;
    const int c  = bc & (NC - 1);       // chunk index (wave-uniform)
    const int b  = bc >> 9;
    const int t0 = c * L;
    const int t1 = t0 + L;

    const f32x4* __restrict__ x4 = (const f32x4*)x;
    f32x4* __restrict__       o4 = (f32x4*)out;
    const size_t base = ((size_t)b * T) * C4 + l;

    const bool hasB = (c > 0);          // wave-uniform
    const bool hasF = (c < NC - 1);

    // ---- issue ALL loads up-front: 8 main + 5 back-halo + 5 fwd-halo ----
    f32x4 hb4[W], hf4[W];
    if (hasB) {
        #pragma unroll
        for (int w = 0; w < W; ++w) hb4[w] = x4[base + (size_t)(t0 - 1 - w) * C4];
    }
    if (hasF) {
        #pragma unroll
        for (int w = 0; w < W; ++w) hf4[w] = x4[base + (size_t)(t1 + w) * C4];
    }
    float v[L][4];
    #pragma unroll
    for (int j = 0; j < L; ++j) {
        f32x4 tv = x4[base + (size_t)(t0 + j) * C4];
        v[j][0] = tv.x; v[j][1] = tv.y; v[j][2] = tv.z; v[j][3] = tv.w;
    }

    // ---- backward halo -> prev carry (pi,pv) ----
    int pi[4]; float pv[4];
    #pragma unroll
    for (int cc = 0; cc < 4; ++cc) { pi[cc] = -1; pv[cc] = 0.0f; }
    if (hasB) {
        #pragma unroll
        for (int w = 0; w < W; ++w) {
            float h[4] = {hb4[w].x, hb4[w].y, hb4[w].z, hb4[w].w};
            #pragma unroll
            for (int cc = 0; cc < 4; ++cc)
                if (pi[cc] < 0 && h[cc] != 0.0f) { pi[cc] = t0 - 1 - w; pv[cc] = h[cc]; }
        }
        // rare deep-run fallback (per-column prob 0.3^6 ~ 0.07%), 2 rows/iter
        int pending = 0;
        #pragma unroll
        for (int cc = 0; cc < 4; ++cc)
            if (v[0][cc] == 0.0f && pi[cc] < 0) pending |= (1 << cc);
        if (pending) {
            int tt = t0 - 1 - W;
            while (pending && tt >= 0) {
                f32x4 a0 = x4[base + (size_t)tt * C4];
                const bool has2 = (tt - 1) >= 0;
                f32x4 a1;
                if (has2) a1 = x4[base + (size_t)(tt - 1) * C4];
                float h0[4] = {a0.x, a0.y, a0.z, a0.w};
                #pragma unroll
                for (int cc = 0; cc < 4; ++cc)
                    if (((pending >> cc) & 1) && h0[cc] != 0.0f) {
                        pi[cc] = tt; pv[cc] = h0[cc]; pending &= ~(1 << cc);
                    }
                if (has2 && pending) {
                    float h1[4] = {a1.x, a1.y, a1.z, a1.w};
                    #pragma unroll
                    for (int cc = 0; cc < 4; ++cc)
                        if (((pending >> cc) & 1) && h1[cc] != 0.0f) {
                            pi[cc] = tt - 1; pv[cc] = h1[cc]; pending &= ~(1 << cc);
                        }
                }
                tt -= 2;
            }
        }
    }

    // ---- forward halo -> next seed (ni,nv) ----
    int ni[4]; float nv[4];
    #pragma unroll
    for (int cc = 0; cc < 4; ++cc) { ni[cc] = T; nv[cc] = 0.0f; }
    if (hasF) {
        #pragma unroll
        for (int w = 0; w < W; ++w) {
            float h[4] = {hf4[w].x, hf4[w].y, hf4[w].z, hf4[w].w};
            #pragma unroll
            for (int cc = 0; cc < 4; ++cc)
                if (ni[cc] == T && h[cc] != 0.0f) { ni[cc] = t1 + w; nv[cc] = h[cc]; }
        }
        int pending = 0;
        #pragma unroll
        for (int cc = 0; cc < 4; ++cc)
            if (v[L - 1][cc] == 0.0f && ni[cc] == T) pending |= (1 << cc);
        if (pending) {
            int tt = t1 + W;
            while (pending && tt < T) {
                f32x4 a0 = x4[base + (size_t)tt * C4];
                const bool has2 = (tt + 1) < T;
                f32x4 a1;
                if (has2) a1 = x4[base + (size_t)(tt + 1) * C4];
                float h0[4] = {a0.x, a0.y, a0.z, a0.w};
                #pragma unroll
                for (int cc = 0; cc < 4; ++cc)
                    if (((pending >> cc) & 1) && h0[cc] != 0.0f) {
                        ni[cc] = tt; nv[cc] = h0[cc]; pending &= ~(1 << cc);
                    }
                if (has2 && pending) {
                    float h1[4] = {a1.x, a1.y, a1.z, a1.w};
                    #pragma unroll
                    for (int cc = 0; cc < 4; ++cc)
                        if (((pending >> cc) & 1) && h1[cc] != 0.0f) {
                            ni[cc] = tt + 1; nv[cc] = h1[cc]; pending &= ~(1 << cc);
                        }
                }
                tt += 2;
            }
        }
    }

    // ---- forward emit: prev-carry + unrolled in-chunk next-scan (R3 form) ----
    #pragma unroll
    for (int j = 0; j < L; ++j) {
        float o[4];
        #pragma unroll
        for (int cc = 0; cc < 4; ++cc) {
            float val = v[j][cc];
            if (val != 0.0f) {
                o[cc] = val; pi[cc] = t0 + j; pv[cc] = val;
            } else {
                // nearest in-chunk next wins (reverse unroll), else halo next
                int nxi = ni[cc]; float nxv = nv[cc];
                #pragma unroll
                for (int k = L - 1; k > j; --k)
                    if (v[k][cc] != 0.0f) { nxi = t0 + k; nxv = v[k][cc]; }
                if (pi[cc] >= 0 && nxi < T) {
                    int denom = nxi - pi[cc] - 2;        // run_len - 1
                    if (denom < 1) denom = 1;
                    float frac = __fdividef((float)(t0 + j - pi[cc] - 1), (float)denom);
                    o[cc] = pv[cc] + (nxv - pv[cc]) * frac;
                } else {
                    o[cc] = 0.0f;                        // boundary-touching run
                }
            }
        }
        f32x4 ov; ov.x = o[0]; ov.y = o[1]; ov.z = o[2]; ov.w = o[3];
        __builtin_nontemporal_store(ov, &o4[base + (size_t)(t0 + j) * C4]);
    }
}

extern "C" void kernel_launch(void* const* d_in, const int* in_sizes, int n_in,
                              void* d_out, int out_size, void* d_ws, size_t ws_size,
                              hipStream_t stream) {
    const float* x = (const float*)d_in[0];
    float* out = (float*)d_out;
    const int total_threads = B * NC * C4;   // 1,048,576
    dim3 grid(total_threads / BLK), block(BLK);
    LinearImputer_kernel<<<grid, block, 0, stream>>>(x, out);
}